// Round 1
// baseline (674.337 us; speedup 1.0000x reference)
//
#include <hip/hip_runtime.h>
#include <cstdint>
#include <cstddef>

// ---------------- CSR build ----------------

__global__ __launch_bounds__(256) void k_deg_init(int* __restrict__ deg, int n) {
    int i = blockIdx.x * 256 + threadIdx.x;
    if (i < n) deg[i] = 1;  // self-loop
}

__global__ __launch_bounds__(256) void k_deg_count(const int* __restrict__ dstv,
                                                   int* __restrict__ deg, int E) {
    int i = blockIdx.x * 256 + threadIdx.x;
    if (i < E) atomicAdd(&deg[dstv[i]], 1);
}

__global__ __launch_bounds__(256) void k_dinv_bsum(const int* __restrict__ deg,
                                                   float* __restrict__ dinv,
                                                   int* __restrict__ bsum, int n) {
    __shared__ int sred[256];
    int t = threadIdx.x;
    int i = blockIdx.x * 256 + t;
    int d = (i < n) ? deg[i] : 0;
    if (i < n) dinv[i] = rsqrtf((float)d);
    sred[t] = d;
    __syncthreads();
    for (int off = 128; off > 0; off >>= 1) {
        if (t < off) sred[t] += sred[t + off];
        __syncthreads();
    }
    if (t == 0) bsum[blockIdx.x] = sred[0];
}

__global__ __launch_bounds__(1024) void k_scan_bsum(int* __restrict__ bsum, int nb) {
    __shared__ int s[1024];
    int t = threadIdx.x;
    int v = (t < nb) ? bsum[t] : 0;
    s[t] = v;
    __syncthreads();
    for (int off = 1; off < 1024; off <<= 1) {
        int x = 0;
        if (t >= off) x = s[t - off];
        __syncthreads();
        if (t >= off) s[t] += x;
        __syncthreads();
    }
    if (t < nb) bsum[t] = s[t] - v;  // exclusive
}

__global__ __launch_bounds__(256) void k_rowstart(const int* __restrict__ deg,
                                                  const int* __restrict__ bsum,
                                                  int* __restrict__ rowstart,
                                                  int* __restrict__ cursor, int n) {
    __shared__ int s[256];
    int t = threadIdx.x;
    int i = blockIdx.x * 256 + t;
    int d = (i < n) ? deg[i] : 0;
    s[t] = d;
    __syncthreads();
    for (int off = 1; off < 256; off <<= 1) {
        int x = 0;
        if (t >= off) x = s[t - off];
        __syncthreads();
        if (t >= off) s[t] += x;
        __syncthreads();
    }
    int incl = s[t];
    int excl = incl - d;
    int base = bsum[blockIdx.x];
    if (i < n) {
        int rs = base + excl;
        rowstart[i] = rs;
        cursor[i] = rs;
        if (i == n - 1) rowstart[n] = base + incl;
    }
}

__global__ __launch_bounds__(256) void k_fill(const int* __restrict__ srcv,
                                              const int* __restrict__ dstv,
                                              int* __restrict__ cursor,
                                              int* __restrict__ colv, int E, int n) {
    int g = blockIdx.x * 256 + threadIdx.x;
    int total = E + n;
    if (g >= total) return;
    int s, d;
    if (g < E) { s = srcv[g]; d = dstv[g]; }
    else       { s = g - E;   d = s; }
    int pos = atomicAdd(&cursor[d], 1);
    colv[pos] = s;
}

// ---------------- f32 tile GEMM: C[M][128] = A[M][K] @ B[K][128] ----------------

template<int K>
__global__ __launch_bounds__(256) void gemm_f32_x128(const float* __restrict__ A,
                                                     const float* __restrict__ B,
                                                     float* __restrict__ C, int M) {
    __shared__ float As[64][68];
    __shared__ float Bs[64][128];
    const int tid = threadIdx.x;
    const int tx = tid & 15;   // 16 col-groups
    const int ty = tid >> 4;   // 16 row-groups (4 rows each)
    const int r0 = blockIdx.x * 64;

    float4 acc0[4], acc1[4];
#pragma unroll
    for (int m = 0; m < 4; ++m) {
        acc0[m] = make_float4(0.f, 0.f, 0.f, 0.f);
        acc1[m] = make_float4(0.f, 0.f, 0.f, 0.f);
    }

    for (int k0 = 0; k0 < K; k0 += 64) {
#pragma unroll
        for (int i = 0; i < 4; ++i) {  // A tile: 64x64 floats
            int idx = tid + i * 256;
            int flat = idx * 4;
            int ar = flat >> 6, ac = flat & 63;
            int grow = r0 + ar;
            float4 v = make_float4(0.f, 0.f, 0.f, 0.f);
            if (grow < M) v = *(const float4*)&A[(size_t)grow * K + k0 + ac];
            *(float4*)&As[ar][ac] = v;
        }
#pragma unroll
        for (int i = 0; i < 8; ++i) {  // B tile: 64x128 floats
            int idx = tid + i * 256;
            int flat = idx * 4;
            int br = flat >> 7, bc = flat & 127;
            *(float4*)&Bs[br][bc] = *(const float4*)&B[(size_t)(k0 + br) * 128 + bc];
        }
        __syncthreads();

#pragma unroll
        for (int k4 = 0; k4 < 16; ++k4) {
            float4 a[4];
#pragma unroll
            for (int m = 0; m < 4; ++m) a[m] = *(const float4*)&As[ty * 4 + m][k4 * 4];
#pragma unroll
            for (int kk = 0; kk < 4; ++kk) {
                float4 b0 = *(const float4*)&Bs[k4 * 4 + kk][tx * 4];
                float4 b1 = *(const float4*)&Bs[k4 * 4 + kk][64 + tx * 4];
#pragma unroll
                for (int m = 0; m < 4; ++m) {
                    float am = ((const float*)&a[m])[kk];
                    acc0[m].x += am * b0.x; acc0[m].y += am * b0.y;
                    acc0[m].z += am * b0.z; acc0[m].w += am * b0.w;
                    acc1[m].x += am * b1.x; acc1[m].y += am * b1.y;
                    acc1[m].z += am * b1.z; acc1[m].w += am * b1.w;
                }
            }
        }
        __syncthreads();
    }

#pragma unroll
    for (int m = 0; m < 4; ++m) {
        int row = r0 + ty * 4 + m;
        if (row < M) {
            *(float4*)&C[(size_t)row * 128 + tx * 4] = acc0[m];
            *(float4*)&C[(size_t)row * 128 + 64 + tx * 4] = acc1[m];
        }
    }
}

// ---------------- GEMM2 fused: [mu|ls] = A@[Wmu|Wls]+b ; z = mu + eps*exp(ls) ----------------

__global__ __launch_bounds__(256) void gemm2_fused(const float* __restrict__ A,  // [M][128]
                                                   const float* __restrict__ Wmu,  // [128][64]
                                                   const float* __restrict__ Wls,  // [128][64]
                                                   const float* __restrict__ bmu,
                                                   const float* __restrict__ bls,
                                                   const float* __restrict__ eps,  // [M][64]
                                                   float* __restrict__ zout,
                                                   float* __restrict__ muout,
                                                   float* __restrict__ lsout, int M) {
    __shared__ float As[64][68];
    __shared__ float Bs[64][128];
    const int tid = threadIdx.x;
    const int tx = tid & 15;
    const int ty = tid >> 4;
    const int r0 = blockIdx.x * 64;
    const int K = 128;

    float4 acc0[4], acc1[4];
#pragma unroll
    for (int m = 0; m < 4; ++m) {
        acc0[m] = make_float4(0.f, 0.f, 0.f, 0.f);
        acc1[m] = make_float4(0.f, 0.f, 0.f, 0.f);
    }

    for (int k0 = 0; k0 < K; k0 += 64) {
#pragma unroll
        for (int i = 0; i < 4; ++i) {
            int idx = tid + i * 256;
            int flat = idx * 4;
            int ar = flat >> 6, ac = flat & 63;
            int grow = r0 + ar;
            float4 v = make_float4(0.f, 0.f, 0.f, 0.f);
            if (grow < M) v = *(const float4*)&A[(size_t)grow * K + k0 + ac];
            *(float4*)&As[ar][ac] = v;
        }
#pragma unroll
        for (int i = 0; i < 8; ++i) {
            int idx = tid + i * 256;
            int flat = idx * 4;
            int br = flat >> 7, bc = flat & 127;
            float4 v;
            if (bc < 64) v = *(const float4*)&Wmu[(size_t)(k0 + br) * 64 + bc];
            else         v = *(const float4*)&Wls[(size_t)(k0 + br) * 64 + (bc - 64)];
            *(float4*)&Bs[br][bc] = v;
        }
        __syncthreads();

#pragma unroll
        for (int k4 = 0; k4 < 16; ++k4) {
            float4 a[4];
#pragma unroll
            for (int m = 0; m < 4; ++m) a[m] = *(const float4*)&As[ty * 4 + m][k4 * 4];
#pragma unroll
            for (int kk = 0; kk < 4; ++kk) {
                float4 b0 = *(const float4*)&Bs[k4 * 4 + kk][tx * 4];
                float4 b1 = *(const float4*)&Bs[k4 * 4 + kk][64 + tx * 4];
#pragma unroll
                for (int m = 0; m < 4; ++m) {
                    float am = ((const float*)&a[m])[kk];
                    acc0[m].x += am * b0.x; acc0[m].y += am * b0.y;
                    acc0[m].z += am * b0.z; acc0[m].w += am * b0.w;
                    acc1[m].x += am * b1.x; acc1[m].y += am * b1.y;
                    acc1[m].z += am * b1.z; acc1[m].w += am * b1.w;
                }
            }
        }
        __syncthreads();
    }

    float4 bm = *(const float4*)&bmu[tx * 4];
    float4 bl = *(const float4*)&bls[tx * 4];
#pragma unroll
    for (int m = 0; m < 4; ++m) {
        int row = r0 + ty * 4 + m;
        if (row < M) {
            float4 mu4, ls4, z4;
            mu4.x = acc0[m].x + bm.x; mu4.y = acc0[m].y + bm.y;
            mu4.z = acc0[m].z + bm.z; mu4.w = acc0[m].w + bm.w;
            ls4.x = acc1[m].x + bl.x; ls4.y = acc1[m].y + bl.y;
            ls4.z = acc1[m].z + bl.z; ls4.w = acc1[m].w + bl.w;
            float4 e4 = *(const float4*)&eps[(size_t)row * 64 + tx * 4];
            z4.x = mu4.x + e4.x * expf(ls4.x);
            z4.y = mu4.y + e4.y * expf(ls4.y);
            z4.z = mu4.z + e4.z * expf(ls4.z);
            z4.w = mu4.w + e4.w * expf(ls4.w);
            *(float4*)&zout[(size_t)row * 64 + tx * 4] = z4;
            *(float4*)&muout[(size_t)row * 64 + tx * 4] = mu4;
            *(float4*)&lsout[(size_t)row * 64 + tx * 4] = ls4;
        }
    }
}

// ---------------- propagation: out[v] = dinv[v] * sum_{c in N(v)} dinv[c]*h[c] (+bias, relu) ----------------

__global__ __launch_bounds__(256) void k_prop(const float* __restrict__ hsrc,
                                              const int* __restrict__ colv,
                                              const int* __restrict__ rowstart,
                                              const float* __restrict__ dinv,
                                              const float* __restrict__ bias,
                                              float* __restrict__ outb, int n, int do_relu) {
    int wid = (blockIdx.x * 256 + threadIdx.x) >> 6;  // one wave per node
    int lane = threadIdx.x & 63;
    if (wid >= n) return;
    int s = rowstart[wid];
    int e = rowstart[wid + 1];
    float ax = 0.f, ay = 0.f;
    int i = s;
    for (; i + 1 < e; i += 2) {
        int c0 = colv[i], c1 = colv[i + 1];
        float w0 = dinv[c0], w1 = dinv[c1];
        float2 v0 = *(const float2*)(hsrc + (size_t)c0 * 128 + lane * 2);
        float2 v1 = *(const float2*)(hsrc + (size_t)c1 * 128 + lane * 2);
        ax += w0 * v0.x; ay += w0 * v0.y;
        ax += w1 * v1.x; ay += w1 * v1.y;
    }
    if (i < e) {
        int c = colv[i];
        float w = dinv[c];
        float2 v = *(const float2*)(hsrc + (size_t)c * 128 + lane * 2);
        ax += w * v.x; ay += w * v.y;
    }
    float dv = dinv[wid];
    ax *= dv; ay *= dv;
    if (bias) { ax += bias[lane * 2]; ay += bias[lane * 2 + 1]; }
    if (do_relu) { ax = fmaxf(ax, 0.f); ay = fmaxf(ay, 0.f); }
    float2* op = (float2*)(outb + (size_t)wid * 128);
    op[lane] = make_float2(ax, ay);
}

// ---------------- launch ----------------

extern "C" void kernel_launch(void* const* d_in, const int* in_sizes, int n_in,
                              void* d_out, int out_size, void* d_ws, size_t ws_size,
                              hipStream_t stream) {
    const float* x   = (const float*)d_in[0];
    const int*   ei  = (const int*)d_in[1];
    const float* W1  = (const float*)d_in[2];
    const float* b1  = (const float*)d_in[3];
    const float* Wmu = (const float*)d_in[4];
    const float* bmu = (const float*)d_in[5];
    const float* Wls = (const float*)d_in[6];
    const float* bls = (const float*)d_in[7];
    const float* eps = (const float*)d_in[8];

    const int n = in_sizes[0] / 256;   // 100000
    const int E = in_sizes[1] / 2;     // 1600000
    const int* srcv = ei;
    const int* dstv = ei + E;

    char* w = (char*)d_ws;
    auto alloc = [&](size_t bytes) -> char* {
        char* p = w;
        w += (bytes + 255) & ~(size_t)255;
        return p;
    };
    int*   deg      = (int*)alloc((size_t)n * 4);
    float* dinv     = (float*)alloc((size_t)n * 4);
    int*   rowstart = (int*)alloc((size_t)(n + 1) * 4);
    int*   cursor   = (int*)alloc((size_t)n * 4);
    int*   bsum     = (int*)alloc(4096);
    int*   colv     = (int*)alloc((size_t)(E + n) * 4);
    float* h        = (float*)alloc((size_t)n * 128 * 4);
    float* hidden   = (float*)alloc((size_t)n * 128 * 4);
    float* agg2     = h;  // reuse h after hidden is computed

    const int nb = (n + 255) / 256;

    k_deg_init<<<nb, 256, 0, stream>>>(deg, n);
    k_deg_count<<<(E + 255) / 256, 256, 0, stream>>>(dstv, deg, E);
    k_dinv_bsum<<<nb, 256, 0, stream>>>(deg, dinv, bsum, n);
    k_scan_bsum<<<1, 1024, 0, stream>>>(bsum, nb);
    k_rowstart<<<nb, 256, 0, stream>>>(deg, bsum, rowstart, cursor, n);
    k_fill<<<(E + n + 255) / 256, 256, 0, stream>>>(srcv, dstv, cursor, colv, E, n);

    gemm_f32_x128<256><<<(n + 63) / 64, 256, 0, stream>>>(x, W1, h, n);
    k_prop<<<(n + 3) / 4, 256, 0, stream>>>(h, colv, rowstart, dinv, b1, hidden, n, 1);
    k_prop<<<(n + 3) / 4, 256, 0, stream>>>(hidden, colv, rowstart, dinv, nullptr, agg2, n, 0);

    float* zout  = (float*)d_out;
    float* muout = zout + (size_t)n * 64;
    float* lsout = muout + (size_t)n * 64;
    gemm2_fused<<<(n + 63) / 64, 256, 0, stream>>>(agg2, Wmu, Wls, bmu, bls, eps,
                                                   zout, muout, lsout, n);
}